// Round 7
// baseline (550.218 us; speedup 1.0000x reference)
//
#include <hip/hip_runtime.h>
#include <math.h>

#define L_  50
#define T_  100
#define NEG_INF_ -9000000000000000.0f

using bf16x8 = __attribute__((ext_vector_type(8))) short;
using f32x4 = __attribute__((ext_vector_type(4))) float;

__device__ __forceinline__ float wred_sum(float v) {
#pragma unroll
    for (int o = 32; o > 0; o >>= 1) v += __shfl_xor(v, o, 64);
    return v;
}
__device__ __forceinline__ short f2bf(float f) {  // RNE fp32 -> bf16 bits
    unsigned u = __float_as_uint(f);
    return (short)((u + 0x7fffu + ((u >> 16) & 1u)) >> 16);
}
__device__ __forceinline__ unsigned short f2bfu(float f) {
    unsigned u = __float_as_uint(f);
    return (unsigned short)((u + 0x7fffu + ((u >> 16) & 1u)) >> 16);
}
__device__ __forceinline__ float bf2f(unsigned short u) {
    return __uint_as_float(((unsigned)u) << 16);
}
// tanh via exp+rcp: ~7 instr, |rel err| ~1e-7
__device__ __forceinline__ float tanh_fast(float x) {
    const float cx = fminf(fmaxf(x, -15.f), 15.f);
    const float t = __expf(2.f * cx);
    return (t - 1.f) * __builtin_amdgcn_rcpf(t + 1.f);
}

// ---------------- pre-pass: W -> bf16 MFMA B-frags ---------------------------
// mats 0,1 (W_att, W_out): 9 N-tiles; tile 8 = [W@a1 | W@a2 | 0...] (f1/f2 fold).
// mat 2 (att1_W): 8 N-tiles.
extern "C" __global__ void __launch_bounds__(256) magnn_preswizzle(
    const float* __restrict__ W0, const float* __restrict__ W1,
    const float* __restrict__ W2, const float* __restrict__ a0,
    const float* __restrict__ a1v, unsigned short* __restrict__ out) {
    const int t = blockIdx.x * 256 + threadIdx.x;  // 104 groups x 64 lanes
    const int gid = t >> 6, lane = t & 63;
    if (gid >= 104) return;
    int mat, kt, nt;
    size_t base;
    if (gid < 72) {
        mat = gid / 36;
        const int rem = gid % 36;
        kt = rem / 9;
        nt = rem % 9;
        base = (size_t)mat * 18432 + (size_t)(((kt * 9 + nt) * 64 + lane) << 3);
    } else {
        mat = 2;
        const int rem = gid - 72;
        kt = rem >> 3;
        nt = rem & 7;
        base = 36864 + (size_t)(((kt * 8 + nt) * 64 + lane) << 3);
    }
    const float* Ws = (mat == 0) ? W0 : (mat == 1) ? W1 : W2;
    const int n = lane & 15;
    const int k0 = kt * 32 + (lane >> 4) * 8;
    bf16x8 v;
    if (nt < 8) {
        const int col = nt * 16 + n;
#pragma unroll
        for (int j = 0; j < 8; ++j) v[j] = f2bf(Ws[(size_t)(k0 + j) * 128 + col]);
    } else {
        if (n < 2) {  // col 128 -> W@a1, col 129 -> W@a2
            const float* av = ((mat == 0) ? a0 : a1v) + n * 128;
#pragma unroll
            for (int j = 0; j < 8; ++j) {
                float s = 0.f;
                const float* wr = Ws + (size_t)(k0 + j) * 128;
                for (int g = 0; g < 128; ++g) s = fmaf(wr[g], av[g], s);
                v[j] = f2bf(s);
            }
        } else {
#pragma unroll
            for (int j = 0; j < 8; ++j) v[j] = 0;
        }
    }
    *(bf16x8*)(out + base) = v;
}

extern "C" __global__ void __launch_bounds__(256, 5) magnn_fused(
    const int* __restrict__ iseq, const int* __restrict__ uids,
    const int* __restrict__ itp, const int* __restrict__ A,
    const float* __restrict__ item_emb, const float* __restrict__ user_emb,
    const float* __restrict__ W2t, const float* __restrict__ b2t,
    const float* __restrict__ att1_b, const float* __restrict__ att2_W,
    const float* __restrict__ att2_b, const float* __restrict__ user_com,
    const unsigned short* __restrict__ Wb, float* __restrict__ out) {
    // LDS: xb 13600 + ht 18432 + fsc 512 = 32544 -> alloc 32768 -> 5 blocks/CU.
    __shared__ __align__(16) unsigned short xb[50][136];  // x (bf16, row-major)
    __shared__ __align__(16) unsigned short ht[128][72];  // h^T (bf16, col-major)
    __shared__ __align__(16) float fsc[128];
    float* f1s = fsc;
    float* f2s = fsc + 64;
    // P (attn matrix) aliases xb: x is dead from post-GEMM until P@h stores
    // (extra barrier inside P@h makes the x' overwrite safe).
    unsigned short (*Pb)[72] = (unsigned short (*)[72]) & xb[0][0];
    // post-GAT scratch in dead ht:
    float* attn4 = (float*)&ht[0][0];  // [200] 50 x float4
    float* cat = attn4 + 256;          // [256]
    float* fpart = cat + 256;          // [128]
    float* vvec = fpart + 128;         // [128]

    const int tid = threadIdx.x;
    const int b = blockIdx.x;
    const int w = tid >> 6, lane = tid & 63;
    const int n16 = lane & 15, quad = lane >> 4;

    // ---- gather item embeddings -> xb (bf16); sval exact fp32 from global ----
    const int* isq = iseq + b * L_;
    for (int i = tid; i < L_ * 32; i += 256) {
        const int l = i >> 5, c4 = (i & 31) << 2;
        const float4 v = *(const float4*)&item_emb[(size_t)isq[l] * 128 + c4];
        ushort4 pk;
        pk.x = f2bfu(v.x); pk.y = f2bfu(v.y); pk.z = f2bfu(v.z); pk.w = f2bfu(v.w);
        *(ushort4*)&xb[l][c4] = pk;
    }
    float sval = 0.f;
    if (tid < 128) {
#pragma unroll 5
        for (int l = 0; l < L_; ++l)
            sval += item_emb[(size_t)isq[l] * 128 + tid];  // L1/L2-hot re-read
    }
    __syncthreads();

    // ---- 2 GAT layers ----
#pragma unroll 1
    for (int layer = 0; layer < 2; ++layer) {
        // GEMM: ht = x @ W (9th tile folds f1/f2)
        {
            const unsigned short* Wl = Wb + layer * 18432;
            const int mrd = w * 16 + n16;
            const int mr = (mrd < 50) ? mrd : 49;
            f32x4 acc[9];
#pragma unroll
            for (int nt = 0; nt < 9; ++nt) acc[nt] = (f32x4){0.f, 0.f, 0.f, 0.f};
#pragma unroll
            for (int kt = 0; kt < 4; ++kt) {
                const bf16x8 af = *(const bf16x8*)&xb[mr][kt * 32 + quad * 8];
                const unsigned short* bp = Wl + (((kt * 9) * 64 + lane) << 3);
#pragma unroll
                for (int nt = 0; nt < 9; ++nt) {
                    const bf16x8 bfr = *(const bf16x8*)(bp + (nt << 9));
                    acc[nt] = __builtin_amdgcn_mfma_f32_16x16x32_bf16(af, bfr,
                                                                      acc[nt], 0, 0, 0);
                }
            }
            const int rbase = w * 16 + quad * 4;
#pragma unroll
            for (int nt = 0; nt < 8; ++nt) {
                const int col = nt * 16 + n16;
                ushort4 pk;
                pk.x = f2bfu(acc[nt][0]);
                pk.y = f2bfu(acc[nt][1]);
                pk.z = f2bfu(acc[nt][2]);
                pk.w = f2bfu(acc[nt][3]);
                *(ushort4*)&ht[col][rbase] = pk;
            }
            if (n16 < 2) {
                float* fs = n16 ? f2s : f1s;
#pragma unroll
                for (int reg = 0; reg < 4; ++reg) fs[rbase + reg] = acc[8][reg];
            }
        }
        __syncthreads();
        // masked softmax -> Pb (aliases xb; x dead). exp(e-1): e<=1, no max-red.
        {
            const int* Ab = A + (size_t)b * (L_ * L_);
            const bool nb = lane < L_;
            const float f2v = nb ? f2s[lane] : 0.f;
#pragma unroll 2
            for (int k = 0; k < 13; ++k) {
                const int l = w + 4 * k;
                if (l < L_) {
                    const int adj = nb ? Ab[l * L_ + lane] : 0;
                    const unsigned long long bal = __ballot(adj > 0);
                    float p;
                    if (bal) {
                        const float e = tanh_fast(f1s[l] + f2v);
                        p = (adj > 0) ? __expf(e - 1.f) : 0.f;
                    } else {
                        p = nb ? 1.f : 0.f;  // all-masked: JAX uniform 1/50
                    }
                    const float s = wred_sum(p);
                    Pb[l][lane] = f2bfu(p * __builtin_amdgcn_rcpf(s));
                }
            }
        }
        __syncthreads();
        // h' = P @ h via MFMA; elu -> xb (load P frags, barrier, then store)
        {
            const int pm = w * 16 + n16;
            const int pmc = (pm < 50) ? pm : 49;
            const bf16x8 pa0 = *(const bf16x8*)&Pb[pmc][quad * 8];
            const bf16x8 pa1 = *(const bf16x8*)&Pb[pmc][32 + quad * 8];
            __syncthreads();  // all P reads done before xb overwritten
            f32x4 oacc[8];
#pragma unroll
            for (int nt = 0; nt < 8; ++nt) oacc[nt] = (f32x4){0.f, 0.f, 0.f, 0.f};
#pragma unroll
            for (int nt = 0; nt < 8; ++nt) {
                const bf16x8 h0 = *(const bf16x8*)&ht[nt * 16 + n16][quad * 8];
                oacc[nt] = __builtin_amdgcn_mfma_f32_16x16x32_bf16(pa0, h0,
                                                                   oacc[nt], 0, 0, 0);
            }
#pragma unroll
            for (int nt = 0; nt < 8; ++nt) {
                const bf16x8 h1 = *(const bf16x8*)&ht[nt * 16 + n16][32 + quad * 8];
                oacc[nt] = __builtin_amdgcn_mfma_f32_16x16x32_bf16(pa1, h1,
                                                                   oacc[nt], 0, 0, 0);
            }
            const int rb = w * 16 + quad * 4;
#pragma unroll
            for (int nt = 0; nt < 8; ++nt) {
#pragma unroll
                for (int reg = 0; reg < 4; ++reg) {
                    const int row = rb + reg;
                    if (row < L_) {
                        float e = oacc[nt][reg];
                        e = (e > 0.f) ? e : (__expf(e) - 1.f);
                        xb[row][nt * 16 + n16] = f2bfu(e);
                    }
                }
            }
        }
        __syncthreads();
    }

    // ---- m1 GEMM + in-register m2 + softmax(H=4) -> attn4 (m1 never stored) --
    {
        const unsigned short* Wl = Wb + 36864;
        const int mrd = w * 16 + n16;
        const int mr = (mrd < 50) ? mrd : 49;
        f32x4 acc[8];
#pragma unroll
        for (int nt = 0; nt < 8; ++nt) acc[nt] = (f32x4){0.f, 0.f, 0.f, 0.f};
#pragma unroll
        for (int kt = 0; kt < 4; ++kt) {
            const bf16x8 af = *(const bf16x8*)&xb[mr][kt * 32 + quad * 8];
            const unsigned short* bp = Wl + (((kt * 8) * 64 + lane) << 3);
#pragma unroll
            for (int nt = 0; nt < 8; ++nt) {
                const bf16x8 bfr = *(const bf16x8*)(bp + (nt << 9));
                acc[nt] = __builtin_amdgcn_mfma_f32_16x16x32_bf16(af, bfr,
                                                                  acc[nt], 0, 0, 0);
            }
        }
        // m1[row][col] = tanh(acc + b1[col]); m2[row][h] = sum_col m1*att2_W[col][h]
        float m2p[4][4];  // [reg][h]
#pragma unroll
        for (int reg = 0; reg < 4; ++reg)
#pragma unroll
            for (int hh = 0; hh < 4; ++hh) m2p[reg][hh] = 0.f;
#pragma unroll
        for (int nt = 0; nt < 8; ++nt) {
            const int col = nt * 16 + n16;
            const float b1 = att1_b[col];
            const float4 aw = *(const float4*)&att2_W[col * 4];
#pragma unroll
            for (int reg = 0; reg < 4; ++reg) {
                const float m1v = tanh_fast(acc[nt][reg] + b1);
                m2p[reg][0] = fmaf(m1v, aw.x, m2p[reg][0]);
                m2p[reg][1] = fmaf(m1v, aw.y, m2p[reg][1]);
                m2p[reg][2] = fmaf(m1v, aw.z, m2p[reg][2]);
                m2p[reg][3] = fmaf(m1v, aw.w, m2p[reg][3]);
            }
        }
        // reduce across the 16 lanes of the quad (same rows)
#pragma unroll
        for (int reg = 0; reg < 4; ++reg)
#pragma unroll
            for (int hh = 0; hh < 4; ++hh) {
                float v = m2p[reg][hh];
#pragma unroll
                for (int o = 8; o > 0; o >>= 1) v += __shfl_xor(v, o, 64);
                m2p[reg][hh] = v;
            }
        const float bb0 = att2_b[0], bb1 = att2_b[1], bb2 = att2_b[2], bb3 = att2_b[3];
        const int rbase = w * 16 + quad * 4;
#pragma unroll
        for (int reg = 0; reg < 4; ++reg) {
            const float v0 = m2p[reg][0] + bb0, v1 = m2p[reg][1] + bb1;
            const float v2 = m2p[reg][2] + bb2, v3 = m2p[reg][3] + bb3;
            const float mx = fmaxf(fmaxf(v0, v1), fmaxf(v2, v3));
            const float e0 = __expf(v0 - mx), e1 = __expf(v1 - mx);
            const float e2 = __expf(v2 - mx), e3 = __expf(v3 - mx);
            const float inv = 1.f / (e0 + e1 + e2 + e3);
            const int row = rbase + reg;
            if (n16 == 0 && row < L_)
                *(float4*)&attn4[row * 4] =
                    make_float4(e0 * inv, e1 * inv, e2 * inv, e3 * inv);
        }
    }
    __syncthreads();

    // ---- matrix_z -> cat[0:128]; user_emb -> cat[128:256] ----
    {
        float zval;
        if (tid < 128) {
            const int d = tid;
            float z0 = 0.f, z1 = 0.f, z2 = 0.f, z3 = 0.f;
            for (int l = 0; l < L_; ++l) {
                const float xv = bf2f(xb[l][d]);
                const float4 at = *(const float4*)&attn4[l * 4];  // broadcast
                z0 = fmaf(xv, at.x, z0);
                z1 = fmaf(xv, at.y, z1);
                z2 = fmaf(xv, at.z, z2);
                z3 = fmaf(xv, at.w, z3);
            }
            zval = 0.25f * (tanh_fast(z0) + tanh_fast(z1) +
                            tanh_fast(z2) + tanh_fast(z3));
        } else {
            zval = user_emb[(size_t)uids[b] * 128 + (tid - 128)];
        }
        cat[tid] = zval;  // disjoint from attn4
    }
    __syncthreads();

    // ---- fusion = cat @ user_com; v = fusion + s ----
    {
        const int g = tid & 127, hf = tid >> 7;
        const float* ucb = user_com + hf * 128 * 128 + g;
        const float* cc = cat + hf * 128;
        float acc = 0.f;
#pragma unroll 4
        for (int k = 0; k < 128; ++k) acc = fmaf(cc[k], ucb[(size_t)k * 128], acc);
        if (hf) fpart[g] = acc;
        __syncthreads();
        if (!hf) vvec[g] = acc + fpart[g] + sval;
    }
    __syncthreads();

    // ---- out[b,t] = w2[t]·v + b2[t], 4 reductions in flight ----
    {
        const float vl = vvec[lane], vh = vvec[lane + 64];
        const int* itpb = itp + b * T_;
        for (int base = w; base < T_; base += 16) {
            float r[4];
            int it4[4];
            bool vv[4];
#pragma unroll
            for (int j = 0; j < 4; ++j) {
                const int t = base + 4 * j;
                vv[j] = t < T_;
                it4[j] = vv[j] ? itpb[t] : 0;
                const float* w2r = W2t + (size_t)it4[j] * 128;
                r[j] = vv[j] ? fmaf(w2r[lane], vl, w2r[lane + 64] * vh) : 0.f;
            }
#pragma unroll
            for (int j = 0; j < 4; ++j) r[j] = wred_sum(r[j]);
            if (lane == 0) {
#pragma unroll
                for (int j = 0; j < 4; ++j)
                    if (vv[j]) out[b * T_ + base + 4 * j] = r[j] + b2t[it4[j]];
            }
        }
    }
}

extern "C" void kernel_launch(void* const* d_in, const int* in_sizes, int n_in,
                              void* d_out, int out_size, void* d_ws, size_t ws_size,
                              hipStream_t stream) {
    const int* iseq = (const int*)d_in[0];
    const int* uids = (const int*)d_in[1];
    const int* itp = (const int*)d_in[2];
    const int* A = (const int*)d_in[3];
    const float* item_emb = (const float*)d_in[4];
    const float* user_emb = (const float*)d_in[5];
    const float* W2t = (const float*)d_in[6];
    const float* b2t = (const float*)d_in[7];
    const float* W_att = (const float*)d_in[8];
    const float* a_att = (const float*)d_in[9];
    const float* W_out = (const float*)d_in[10];
    const float* a_out = (const float*)d_in[11];
    const float* att1_W = (const float*)d_in[12];
    const float* att1_b = (const float*)d_in[13];
    const float* att2_W = (const float*)d_in[14];
    const float* att2_b = (const float*)d_in[15];
    const float* user_com = (const float*)d_in[16];
    float* out = (float*)d_out;
    unsigned short* Wb = (unsigned short*)d_ws;  // 53248 bf16 = 104 KiB

    magnn_preswizzle<<<dim3(26), dim3(256), 0, stream>>>(W_att, W_out, att1_W,
                                                         a_att, a_out, Wb);

    const int B = in_sizes[1];  // user_ids is (B,)
    magnn_fused<<<dim3(B), dim3(256), 0, stream>>>(
        iseq, uids, itp, A, item_emb, user_emb, W2t, b2t, att1_b, att2_W,
        att2_b, user_com, Wb, out);
}